// Round 3
// baseline (391.145 us; speedup 1.0000x reference)
//
#include <hip/hip_runtime.h>

// avg_voxelize, counting-sort pipeline. B=8, C=64, N=65536, r=32.
// d_out = [ vox (B*C*r^3 f32) | norm_coords (B*3*N f32) ]
//
// Tier-1 ws layout (needs ~87 MB):
//   cnt    B*R3*16 u32 (padded: 1 bin per 64 B -> kills atomic line contention)
//   off    B*(R3+1) u32
//   packed B*N u32          (idx<<17 | rank)
//   sorted B*N*C bf16 (64 MB)  features permuted to [b][pos][c]
// Tier-2 fallback (~6.3 MB, the round-2 pipeline): dense cnt + pos + gather.

#define BB 8
#define CC 64
#define NN 65536
#define RR 32
#define R3 (RR * RR * RR)          // 32768
#define OFFSTRIDE (R3 + 1)

static __device__ inline unsigned short f2bf(float x) {   // RNE f32->bf16
    unsigned int u = __float_as_uint(x);
    u += 0x7FFFu + ((u >> 16) & 1u);
    return (unsigned short)(u >> 16);
}

__global__ __launch_bounds__(256) void points_kernel(
    const float* __restrict__ coords,     // [B,3,N]
    float* __restrict__ norm_out,         // [B,3,N]
    unsigned int* __restrict__ cnt,       // [B,R3*stride], pre-zeroed
    unsigned int* __restrict__ packed,    // [B,N]
    int cstride)
{
    int gid = blockIdx.x * 256 + threadIdx.x;
    int b = gid >> 16;
    int n = gid & (NN - 1);

    const float* cb = coords + (size_t)b * 3 * NN;
    float x = cb[n];
    float y = cb[NN + n];
    float z = cb[2 * NN + n];

    float nx = fminf(fmaxf(x * (float)RR, 0.0f), (float)(RR - 1));
    float ny = fminf(fmaxf(y * (float)RR, 0.0f), (float)(RR - 1));
    float nz = fminf(fmaxf(z * (float)RR, 0.0f), (float)(RR - 1));

    float* nb = norm_out + (size_t)b * 3 * NN;
    nb[n] = nx;
    nb[NN + n] = ny;
    nb[2 * NN + n] = nz;

    int vx = (int)rintf(nx);   // jnp.round = RNE
    int vy = (int)rintf(ny);
    int vz = (int)rintf(nz);
    unsigned int idx = (unsigned int)((vx * RR + vy) * RR + vz);

    unsigned int rank = atomicAdd(&cnt[(size_t)(b * R3 + idx) * cstride], 1u);
    packed[gid] = (idx << 17) | rank;
}

// One block per batch: exclusive prefix sum of cnt (strided bins) -> dense off
__global__ __launch_bounds__(1024) void scan_kernel(
    const unsigned int* __restrict__ cnt,
    unsigned int* __restrict__ off,
    int cstride)
{
    int b = blockIdx.x;
    int t = threadIdx.x;
    const unsigned int* c = cnt + (size_t)b * R3 * cstride;
    unsigned int* o = off + (size_t)b * OFFSTRIDE;

    unsigned int loc[32];
    unsigned int s = 0;
    #pragma unroll
    for (int k = 0; k < 32; k++) { loc[k] = c[(size_t)(t * 32 + k) * cstride]; s += loc[k]; }

    __shared__ unsigned int aux[1024];
    aux[t] = s;
    __syncthreads();
    for (int d = 1; d < 1024; d <<= 1) {
        unsigned int v = (t >= d) ? aux[t - d] : 0u;
        __syncthreads();
        aux[t] += v;
        __syncthreads();
    }
    unsigned int run = (t == 0) ? 0u : aux[t - 1];
    #pragma unroll
    for (int k = 0; k < 32; k++) { o[t * 32 + k] = run; run += loc[k]; }
    if (t == 1023) o[R3] = run;   // == NN
}

// ---------------- Tier 1: permute (transpose + scatter) + reduce ----------------

// Block = 256 thr, tile = 64 n x 64 c. Reads feats coalesced, LDS transpose
// (stride 65 -> 2-way max), writes sorted[b][p][0:64] bf16: 128 B per point.
__global__ __launch_bounds__(256) void permute_kernel(
    const float* __restrict__ feats,        // [B,C,N]
    const unsigned int* __restrict__ packed,
    const unsigned int* __restrict__ off,
    unsigned short* __restrict__ sorted)    // [B,N,C] bf16 bits
{
    __shared__ float tile[64 * 65];
    __shared__ unsigned int posb[64];

    int n0 = blockIdx.x * 64;
    int b = blockIdx.y;
    int t = threadIdx.x;
    const float* f = feats + (size_t)b * CC * NN;

    #pragma unroll
    for (int it = 0; it < 4; it++) {
        int c  = (t >> 4) + 16 * it;
        int no = (t & 15) * 4;
        float4 fv = *(const float4*)(f + (size_t)c * NN + n0 + no);
        tile[(no + 0) * 65 + c] = fv.x;
        tile[(no + 1) * 65 + c] = fv.y;
        tile[(no + 2) * 65 + c] = fv.z;
        tile[(no + 3) * 65 + c] = fv.w;
    }
    if (t < 64) {
        unsigned int pk = packed[(size_t)b * NN + n0 + t];
        posb[t] = off[(size_t)b * OFFSTRIDE + (pk >> 17)] + (pk & 0x1FFFFu);
    }
    __syncthreads();

    int n = t >> 2, q = t & 3;
    unsigned int p = posb[n];
    unsigned int w[8];
    #pragma unroll
    for (int k = 0; k < 8; k++) {
        unsigned short a = f2bf(tile[n * 65 + q * 16 + 2 * k]);
        unsigned short d = f2bf(tile[n * 65 + q * 16 + 2 * k + 1]);
        w[k] = (unsigned int)a | ((unsigned int)d << 16);
    }
    unsigned short* dst = sorted + ((size_t)b * NN + p) * CC + q * 16;
    uint4 lo = make_uint4(w[0], w[1], w[2], w[3]);
    uint4 hi = make_uint4(w[4], w[5], w[6], w[7]);
    *(uint4*)dst = lo;
    *((uint4*)dst + 1) = hi;
}

// Block = 256 thr (4 waves), 128 voxels/block, lane = channel.
// One coalesced 128 B read per point; no divergence (all lanes share run).
__global__ __launch_bounds__(256) void reduce_kernel(
    const unsigned short* __restrict__ sorted,
    const unsigned int* __restrict__ off,
    float* __restrict__ out)                // [B,C,R3]
{
    __shared__ float tile[64 * 129];

    int v0 = blockIdx.x * 128;
    int b = blockIdx.y;
    int wave = threadIdx.x >> 6;
    int lane = threadIdx.x & 63;            // = channel
    const unsigned int* O = off + (size_t)b * OFFSTRIDE;
    const unsigned short* S = sorted + (size_t)b * NN * CC;

    for (int w = 0; w < 32; w++) {
        int v = v0 + wave * 32 + w;
        unsigned int s0 = O[v];
        unsigned int s1 = O[v + 1];
        float s = 0.0f;
        for (unsigned int p = s0; p < s1; p++) {
            unsigned int u = (unsigned int)S[(size_t)p * CC + lane] << 16;
            s += __uint_as_float(u);
        }
        float cf = (float)(s1 - s0);
        tile[lane * 129 + wave * 32 + w] = s / fmaxf(cf, 1.0f);
    }
    __syncthreads();

    float* ob = out + (size_t)b * CC * R3 + v0;
    for (int k = 0; k < 32; k++) {
        int id = threadIdx.x + 256 * k;     // 0..8191
        int c = id >> 7;
        int dv = id & 127;
        ob[(size_t)c * R3 + dv] = tile[c * 129 + dv];
    }
}

// ---------------- Tier 2 fallback (round-2 pipeline) ----------------

__global__ __launch_bounds__(256) void pos_kernel(
    const unsigned int* __restrict__ packed,
    const unsigned int* __restrict__ off,
    unsigned int* __restrict__ pos)
{
    int gid = blockIdx.x * 256 + threadIdx.x;
    int b = gid >> 16;
    unsigned int pk = packed[gid];
    pos[gid] = off[(size_t)b * OFFSTRIDE + (pk >> 17)] + (pk & 0x1FFFFu);
}

__global__ __launch_bounds__(1024) void gather_kernel(
    const float* __restrict__ feats,
    const unsigned int* __restrict__ pos,
    const unsigned int* __restrict__ off,
    float* __restrict__ out)
{
    __shared__ unsigned short srt[NN];      // bf16 bits, 128 KB

    int c = blockIdx.x;
    int b = blockIdx.y;
    int t = threadIdx.x;

    const float* f = feats + ((size_t)b * CC + c) * NN;
    const unsigned int* P = pos + (size_t)b * NN;

    for (int n0 = t * 4; n0 < NN; n0 += 1024 * 4) {
        float4 fv = *(const float4*)(f + n0);
        uint4 pv = *(const uint4*)(P + n0);
        srt[pv.x] = f2bf(fv.x);
        srt[pv.y] = f2bf(fv.y);
        srt[pv.z] = f2bf(fv.z);
        srt[pv.w] = f2bf(fv.w);
    }
    __syncthreads();

    const unsigned int* O = off + (size_t)b * OFFSTRIDE;
    float* ob = out + ((size_t)b * CC + c) * R3;
    for (int j = 0; j < 32; j++) {
        int v = t + j * 1024;
        unsigned int s0 = O[v];
        unsigned int s1 = O[v + 1];
        float s = 0.0f;
        for (unsigned int p = s0; p < s1; p++)
            s += __uint_as_float((unsigned int)srt[p] << 16);
        ob[v] = s / fmaxf((float)(s1 - s0), 1.0f);
    }
}

extern "C" void kernel_launch(void* const* d_in, const int* in_sizes, int n_in,
                              void* d_out, int out_size, void* d_ws, size_t ws_size,
                              hipStream_t stream) {
    const float* feats  = (const float*)d_in[0];   // [B,C,N]
    const float* coords = (const float*)d_in[1];   // [B,3,N]

    float* out_vox  = (float*)d_out;
    float* out_norm = out_vox + (size_t)BB * CC * R3;

    char* ws = (char*)d_ws;

    const size_t CNT_PAD_BYTES = (size_t)BB * R3 * 16 * 4;     // 16 MB
    const size_t OFF_BYTES     = (size_t)BB * OFFSTRIDE * 4;   // 1,048,608
    const size_t PACKED_BYTES  = (size_t)BB * NN * 4;          // 2 MB
    const size_t SORTED_BYTES  = (size_t)BB * NN * CC * 2;     // 64 MB
    const size_t NEED1 = CNT_PAD_BYTES + OFF_BYTES + PACKED_BYTES + SORTED_BYTES;

    if (ws_size >= NEED1) {
        unsigned int* cnt    = (unsigned int*)ws;
        unsigned int* off    = (unsigned int*)(ws + CNT_PAD_BYTES);
        unsigned int* packed = (unsigned int*)(ws + CNT_PAD_BYTES + OFF_BYTES);
        unsigned short* sorted = (unsigned short*)(ws + CNT_PAD_BYTES + OFF_BYTES + PACKED_BYTES);

        hipMemsetAsync(cnt, 0, CNT_PAD_BYTES, stream);
        points_kernel<<<(BB * NN) / 256, 256, 0, stream>>>(coords, out_norm, cnt, packed, 16);
        scan_kernel<<<BB, 1024, 0, stream>>>(cnt, off, 16);
        permute_kernel<<<dim3(NN / 64, BB), 256, 0, stream>>>(feats, packed, off, sorted);
        reduce_kernel<<<dim3(R3 / 128, BB), 256, 0, stream>>>(sorted, off, out_vox);
    } else {
        // Tier 2: dense cnt (1 MB) + pos + per-(b,c) LDS gather (round-2 path)
        unsigned int* cnt    = (unsigned int*)ws;
        unsigned int* off    = (unsigned int*)(ws + 1048576);
        unsigned int* packed = (unsigned int*)(ws + 1048576 + OFF_BYTES);
        unsigned int* pos    = (unsigned int*)(ws + 1048576 + OFF_BYTES + PACKED_BYTES);

        hipMemsetAsync(cnt, 0, 1048576, stream);
        points_kernel<<<(BB * NN) / 256, 256, 0, stream>>>(coords, out_norm, cnt, packed, 1);
        scan_kernel<<<BB, 1024, 0, stream>>>(cnt, off, 1);
        pos_kernel<<<(BB * NN) / 256, 256, 0, stream>>>(packed, off, pos);
        gather_kernel<<<dim3(CC, BB), 1024, 0, stream>>>(feats, pos, off, out_vox);
    }
}

// Round 4
// 360.314 us; speedup vs baseline: 1.0856x; 1.0856x over previous
//
#include <hip/hip_runtime.h>

// avg_voxelize counting-sort pipeline. B=8, C=64, N=65536, r=32.
// d_out = [ vox (B*C*r^3 f32) | norm_coords (B*3*N f32) ]
// ws: cnt (padded, 16 MB) | off (B*OFFPAD u32) | packed (2 MB) | pos (2 MB) | chunksum (1 KB)

#define BB 8
#define CC 64
#define NN 65536
#define RR 32
#define R3 32768
#define OFFPAD 32772           // R3+4: keeps each batch's off[] 16B-aligned
#define CSTRIDE 16             // one cnt bin per 64 B: spreads atomic line traffic

static __device__ inline unsigned short f2bf(float x) {   // RNE f32->bf16
    unsigned int u = __float_as_uint(x);
    u += 0x7FFFu + ((u >> 16) & 1u);
    return (unsigned short)(u >> 16);
}
static __device__ inline float bf2f(unsigned short h) {
    return __uint_as_float((unsigned int)h << 16);
}

__global__ __launch_bounds__(256) void points_kernel(
    const float* __restrict__ coords,     // [B,3,N]
    float* __restrict__ norm_out,         // [B,3,N]
    unsigned int* __restrict__ cnt,       // padded, pre-zeroed
    unsigned int* __restrict__ packed)    // [B,N]: (idx<<17)|rank
{
    int gid = blockIdx.x * 256 + threadIdx.x;
    int b = gid >> 16;
    int n = gid & (NN - 1);

    const float* cb = coords + (size_t)b * 3 * NN;
    float x = cb[n];
    float y = cb[NN + n];
    float z = cb[2 * NN + n];

    float nx = fminf(fmaxf(x * (float)RR, 0.0f), (float)(RR - 1));
    float ny = fminf(fmaxf(y * (float)RR, 0.0f), (float)(RR - 1));
    float nz = fminf(fmaxf(z * (float)RR, 0.0f), (float)(RR - 1));

    float* nb = norm_out + (size_t)b * 3 * NN;
    nb[n] = nx;
    nb[NN + n] = ny;
    nb[2 * NN + n] = nz;

    int vx = (int)rintf(nx);   // jnp.round = RNE
    int vy = (int)rintf(ny);
    int vz = (int)rintf(nz);
    unsigned int idx = (unsigned int)((vx * RR + vy) * RR + vz);

    unsigned int rank = atomicAdd(&cnt[(size_t)(b * R3 + idx) * CSTRIDE], 1u);
    packed[gid] = (idx << 17) | rank;
}

// ---- 3-phase parallel scan: 256 chunks of 1024 bins ----

__global__ __launch_bounds__(256) void scan_a(
    const unsigned int* __restrict__ cnt,
    unsigned int* __restrict__ off,          // [B][OFFPAD]
    unsigned int* __restrict__ chunksum)     // [256]
{
    int blk = blockIdx.x;                    // b = blk>>5, chunk = blk&31
    int b = blk >> 5, chunk = blk & 31;
    int t = threadIdx.x;
    const unsigned int* c = cnt + ((size_t)b * R3 + chunk * 1024) * CSTRIDE;

    unsigned int v[4];
    unsigned int s = 0;
    #pragma unroll
    for (int k = 0; k < 4; k++) { v[k] = c[(size_t)(4 * t + k) * CSTRIDE]; s += v[k]; }

    unsigned int incl = s;                   // wave inclusive scan (width 64)
    #pragma unroll
    for (int d = 1; d < 64; d <<= 1) {
        unsigned int o = __shfl_up(incl, d, 64);
        if ((t & 63) >= d) incl += o;
    }
    __shared__ unsigned int wsum[4];
    int w = t >> 6;
    if ((t & 63) == 63) wsum[w] = incl;
    __syncthreads();
    unsigned int woff = 0;
    #pragma unroll
    for (int i = 0; i < 3; i++) if (i < w) woff += wsum[i];

    unsigned int run = woff + incl - s;      // exclusive prefix of this thread's bins
    uint4 ov;
    ov.x = run; run += v[0];
    ov.y = run; run += v[1];
    ov.z = run; run += v[2];
    ov.w = run; run += v[3];
    *(uint4*)(off + (size_t)b * OFFPAD + chunk * 1024 + 4 * t) = ov;
    if (t == 255) chunksum[blk] = run;       // chunk total
}

__global__ __launch_bounds__(256) void scan_b(unsigned int* __restrict__ chunksum)
{
    int t = threadIdx.x;                     // batch = t>>5, lane-in-batch = t&31
    unsigned int s = chunksum[t];
    unsigned int incl = s;
    #pragma unroll
    for (int d = 1; d < 32; d <<= 1) {
        unsigned int o = __shfl_up(incl, d, 32);   // width 32: per-batch segments
        if ((t & 31) >= d) incl += o;
    }
    chunksum[t] = incl - s;                  // exclusive chunk offset
}

__global__ __launch_bounds__(256) void scan_c(
    unsigned int* __restrict__ off, const unsigned int* __restrict__ chunksum)
{
    int blk = blockIdx.x;
    int b = blk >> 5, chunk = blk & 31;
    int t = threadIdx.x;
    unsigned int add = chunksum[blk];
    unsigned int* o = off + (size_t)b * OFFPAD + chunk * 1024 + 4 * t;
    uint4 v = *(uint4*)o;
    v.x += add; v.y += add; v.z += add; v.w += add;
    *(uint4*)o = v;
    if (chunk == 31 && t == 255) off[(size_t)b * OFFPAD + R3] = NN;
}

__global__ __launch_bounds__(256) void pos_kernel(
    const unsigned int* __restrict__ packed,
    const unsigned int* __restrict__ off,
    unsigned int* __restrict__ pos)
{
    int gid = blockIdx.x * 256 + threadIdx.x;
    int b = gid >> 16;
    unsigned int pk = packed[gid];
    pos[gid] = off[(size_t)b * OFFPAD + (pk >> 17)] + (pk & 0x1FFFFu);
}

// One block per (b,c): scatter-stage the row into LDS (bf16, sorted order),
// then each thread stream-reduces its OWN contiguous span of 32 voxels.
// Boundary state lives in static-indexed registers (groups of 4, unrolled).
__global__ __launch_bounds__(1024) void gather_kernel(
    const float* __restrict__ feats,        // [B,C,N]
    const unsigned int* __restrict__ pos,   // [B,N]
    const unsigned int* __restrict__ off,   // [B][OFFPAD]
    float* __restrict__ out)                // [B,C,R3]
{
    __shared__ unsigned short srt[NN];      // 128 KB

    int c = blockIdx.x;
    int b = blockIdx.y;
    int t = threadIdx.x;

    const float* f = feats + ((size_t)b * CC + c) * NN;
    const unsigned int* P = pos + (size_t)b * NN;

    #pragma unroll
    for (int it = 0; it < 16; it++) {
        int n0 = t * 4 + it * 4096;
        float4 fv = *(const float4*)(f + n0);
        uint4 pv = *(const uint4*)(P + n0);
        srt[pv.x] = f2bf(fv.x);
        srt[pv.y] = f2bf(fv.y);
        srt[pv.z] = f2bf(fv.z);
        srt[pv.w] = f2bf(fv.w);
    }
    __syncthreads();

    // 33 boundaries of this thread's voxels [32t, 32t+32)
    const unsigned int* O = off + (size_t)b * OFFPAD + 32 * t;
    unsigned int Ob[33];
    #pragma unroll
    for (int k = 0; k < 8; k++) {
        uint4 u = *(const uint4*)(O + 4 * k);
        Ob[4 * k + 0] = u.x; Ob[4 * k + 1] = u.y;
        Ob[4 * k + 2] = u.z; Ob[4 * k + 3] = u.w;
    }
    Ob[32] = O[32];

    float* ob = out + ((size_t)b * CC + c) * R3 + 32 * t;
    unsigned int p = Ob[0];

    #pragma unroll
    for (int g = 0; g < 8; g++) {
        unsigned int lw = 0;
        #pragma unroll
        for (int j = 0; j < 4; j++)
            lw |= (Ob[4 * g + j + 1] - Ob[4 * g + j]) << (8 * j);  // run lens (u8 ok: Poisson(2))
        unsigned int eg = Ob[4 * g + 4];

        int vj = 0;
        unsigned int rem = lw & 255u;
        unsigned int len = rem;
        float s = 0.0f;
        while (vj < 4 && rem == 0u) {              // leading empty voxels
            ob[4 * g + vj] = 0.0f;
            vj++;
            lw >>= 8; rem = lw & 255u; len = rem;
        }
        while (p < eg) {                           // flat element stream
            s += bf2f(srt[p]);
            p++;
            rem--;
            while (vj < 4 && rem == 0u) {          // close voxel(s)
                ob[4 * g + vj] = s / (float)max(len, 1u);
                s = 0.0f;
                vj++;
                lw >>= 8; rem = lw & 255u; len = rem;
            }
        }
    }
}

extern "C" void kernel_launch(void* const* d_in, const int* in_sizes, int n_in,
                              void* d_out, int out_size, void* d_ws, size_t ws_size,
                              hipStream_t stream) {
    const float* feats  = (const float*)d_in[0];   // [B,C,N]
    const float* coords = (const float*)d_in[1];   // [B,3,N]

    float* out_vox  = (float*)d_out;
    float* out_norm = out_vox + (size_t)BB * CC * R3;

    char* ws = (char*)d_ws;
    const size_t CNT_B  = (size_t)BB * R3 * CSTRIDE * 4;   // 16,777,216
    const size_t OFF_B  = (size_t)BB * OFFPAD * 4;         //  1,048,704
    const size_t PK_B   = (size_t)BB * NN * 4;             //  2,097,152

    unsigned int* cnt      = (unsigned int*)ws;
    unsigned int* off      = (unsigned int*)(ws + CNT_B);
    unsigned int* packed   = (unsigned int*)(ws + CNT_B + OFF_B);
    unsigned int* pos      = (unsigned int*)(ws + CNT_B + OFF_B + PK_B);
    unsigned int* chunksum = (unsigned int*)(ws + CNT_B + OFF_B + 2 * PK_B);

    hipMemsetAsync(cnt, 0, CNT_B, stream);

    points_kernel<<<(BB * NN) / 256, 256, 0, stream>>>(coords, out_norm, cnt, packed);
    scan_a<<<256, 256, 0, stream>>>(cnt, off, chunksum);
    scan_b<<<1, 256, 0, stream>>>(chunksum);
    scan_c<<<256, 256, 0, stream>>>(off, chunksum);
    pos_kernel<<<(BB * NN) / 256, 256, 0, stream>>>(packed, off, pos);
    gather_kernel<<<dim3(CC, BB), 1024, 0, stream>>>(feats, pos, off, out_vox);
}